// Round 1
// baseline (389.196 us; speedup 1.0000x reference)
//
#include <hip/hip_runtime.h>
#include <stdint.h>

#define N_BOX 1024
#define C_CLS 80
#define B_IMG 4
#define K_PER 100
#define K_TOT 300
#define NEGF  (-1e30f)
#define M2    8192   // padded size for final per-image sort (8000 candidates)

// ---- monotone float <-> ordered-uint mapping (total order, bit-exact) ----
__device__ __forceinline__ unsigned int ford(float f) {
    unsigned int u = __float_as_uint(f);
    return (u & 0x80000000u) ? ~u : (u | 0x80000000u);
}
__device__ __forceinline__ float funord(unsigned int o) {
    unsigned int u = (o & 0x80000000u) ? (o ^ 0x80000000u) : ~o;
    return __uint_as_float(u);
}

// IoU matching the numpy/jax float32 arithmetic exactly: no fma contraction.
__device__ __forceinline__ float iou_f(float4 a, float4 b) {
#pragma clang fp contract(off)
    float y1a = fminf(a.x, a.z), y2a = fmaxf(a.x, a.z);
    float x1a = fminf(a.y, a.w), x2a = fmaxf(a.y, a.w);
    float y1b = fminf(b.x, b.z), y2b = fmaxf(b.x, b.z);
    float x1b = fminf(b.y, b.w), x2b = fmaxf(b.y, b.w);
    float ih = fminf(y2a, y2b) - fmaxf(y1a, y1b); ih = fmaxf(ih, 0.0f);
    float iw = fminf(x2a, x2b) - fmaxf(x1a, x1b); iw = fmaxf(iw, 0.0f);
    float inter = ih * iw;
    float aa = (y2a - y1a) * (x2a - x1a);
    float ab = (y2b - y1b) * (x2b - x1b);
    float uni = aa + ab - inter;
    uni = fmaxf(uni, 1e-12f);
    return inter / uni;
}

// Kernel 1: one block per (image, class). Stable-descending sort of 1024
// scores, greedy NMS capped at 100 kept, write (score, box-index) to ws.
__global__ __launch_bounds__(256) void nms_per_class(
        const float* __restrict__ scores,   // [B, N, C]
        const float* __restrict__ boxes,    // [B, N, 1, 4]
        float* __restrict__ ws_score,       // [B*C*K_PER]
        int*   __restrict__ ws_idx)         // [B*C*K_PER]
{
    __shared__ unsigned long long key[N_BOX];   // (ford(score)<<32)|(1023-idx)
    __shared__ float4 bx[N_BOX];
    __shared__ unsigned char alive[N_BOX];      // indexed by SORTED position
    __shared__ int kept_pos[K_PER];
    __shared__ int sh_nvalid, sh_head, sh_kept, sh_cur;

    const int tid = threadIdx.x;
    const int b = blockIdx.x / C_CLS;
    const int c = blockIdx.x % C_CLS;

    if (tid == 0) { sh_nvalid = 0; sh_head = 0; sh_kept = 0; }
    __syncthreads();

    int local_valid = 0;
    for (int n = tid; n < N_BOX; n += 256) {
        float s = scores[(size_t)(b * N_BOX + n) * C_CLS + c];
        bool valid = s > 0.001f;                      // SCORE_THR
        float sv = valid ? s : NEGF;
        key[n] = ((unsigned long long)ford(sv) << 32) |
                 (unsigned int)(N_BOX - 1 - n);       // stable: low idx first
        local_valid += valid ? 1 : 0;
        bx[n] = *((const float4*)(boxes + (size_t)(b * N_BOX + n) * 4));
        alive[n] = 1;
    }
    if (local_valid) atomicAdd(&sh_nvalid, local_valid);
    __syncthreads();

    // bitonic sort, DESCENDING on the packed key
    for (int k = 2; k <= N_BOX; k <<= 1) {
        for (int j = k >> 1; j > 0; j >>= 1) {
            for (int i = tid; i < N_BOX; i += 256) {
                int ixj = i ^ j;
                if (ixj > i) {
                    unsigned long long a = key[i], q = key[ixj];
                    bool up = (i & k) == 0;
                    if (up ? (a < q) : (a > q)) { key[i] = q; key[ixj] = a; }
                }
            }
            __syncthreads();
        }
    }

    const int nvalid = sh_nvalid;

    // greedy NMS: sequential head, parallel suppression, stop at 100 kept
    for (;;) {
        if (tid == 0) {
            int h = sh_head;
            while (h < nvalid && !alive[h]) h++;
            sh_head = h;
            sh_cur = (h < nvalid && sh_kept < K_PER) ? h : -1;
        }
        __syncthreads();
        int cur = sh_cur;
        if (cur < 0) break;
        int idx_cur = (N_BOX - 1) - (int)(unsigned int)(key[cur] & 0xFFFFFFFFull);
        float4 kb = bx[idx_cur];
        for (int jj = cur + 1 + tid; jj < nvalid; jj += 256) {
            if (alive[jj]) {
                int idx_j = (N_BOX - 1) - (int)(unsigned int)(key[jj] & 0xFFFFFFFFull);
                if (iou_f(kb, bx[idx_j]) > 0.5f) alive[jj] = 0;
            }
        }
        if (tid == 0) {
            kept_pos[sh_kept++] = cur;
            sh_head = cur + 1;
        }
        __syncthreads();
    }

    if (tid < K_PER) {
        int outbase = (b * C_CLS + c) * K_PER + tid;
        if (tid < sh_kept) {
            unsigned long long kk = key[kept_pos[tid]];
            ws_score[outbase] = funord((unsigned int)(kk >> 32));
            ws_idx[outbase]   = (N_BOX - 1) - (int)(unsigned int)(kk & 0xFFFFFFFFull);
        } else {
            ws_score[outbase] = NEGF;
            ws_idx[outbase]   = 0;
        }
    }
}

// Kernel 2: one block per image. Sort all 8000 candidates (pad to 8192),
// emit top-300 with box gather + clip, class id, and valid count.
__global__ __launch_bounds__(1024) void final_topk(
        const float* __restrict__ ws_score,
        const int*   __restrict__ ws_idx,
        const float* __restrict__ boxes,    // [B, N, 1, 4]
        float* __restrict__ out)
{
    __shared__ unsigned long long key[M2];  // 64 KiB
    const int tid = threadIdx.x;
    const int b = blockIdx.x;
    const int base = b * (C_CLS * K_PER);   // 8000 per image

    for (int i = tid; i < M2; i += 1024) {
        float s = (i < C_CLS * K_PER) ? ws_score[base + i] : NEGF;
        // low bits: lower flat index sorts FIRST among equal scores (lax.top_k)
        key[i] = ((unsigned long long)ford(s) << 32) | (unsigned int)(M2 - 1 - i);
    }
    __syncthreads();

    for (int k = 2; k <= M2; k <<= 1) {
        for (int j = k >> 1; j > 0; j >>= 1) {
            for (int i = tid; i < M2; i += 1024) {
                int ixj = i ^ j;
                if (ixj > i) {
                    unsigned long long a = key[i], q = key[ixj];
                    bool up = (i & k) == 0;
                    if (up ? (a < q) : (a > q)) { key[i] = q; key[ixj] = a; }
                }
            }
            __syncthreads();
        }
    }

    float* out_s = out;                         // [B,300]
    float* out_b = out + B_IMG * K_TOT;         // [B,300,4]
    float* out_c = out + B_IMG * K_TOT * 5;     // [B,300]
    float* out_n = out + B_IMG * K_TOT * 6;     // [B]

    if (tid < K_TOT) {
        unsigned long long kk = key[tid];
        float s = funord((unsigned int)(kk >> 32));
        int flat = (M2 - 1) - (int)(unsigned int)(kk & 0xFFFFFFFFull);
        bool valid = s > (-5e29f);              // top_s > NEG/2
        float os = 0.0f, oc = 0.0f;
        float4 ob = make_float4(0.0f, 0.0f, 0.0f, 0.0f);
        if (valid) {
            int cc = flat / K_PER;
            int n  = ws_idx[base + flat];
            float4 bb = *((const float4*)(boxes + (size_t)(b * N_BOX + n) * 4));
            os = s;
            oc = (float)cc;
            ob.x = fminf(fmaxf(bb.x, 0.0f), 1.0f);
            ob.y = fminf(fmaxf(bb.y, 0.0f), 1.0f);
            ob.z = fminf(fmaxf(bb.z, 0.0f), 1.0f);
            ob.w = fminf(fmaxf(bb.w, 0.0f), 1.0f);
        }
        out_s[b * K_TOT + tid] = os;
        ((float4*)out_b)[b * K_TOT + tid] = ob;
        out_c[b * K_TOT + tid] = oc;
    }
    if (tid == 0) {
        int cnt = 0;
        for (int i = 0; i < K_TOT; i++) {
            float s = funord((unsigned int)(key[i] >> 32));
            if (s > (-5e29f)) cnt++;
        }
        out_n[b] = (float)cnt;
    }
}

extern "C" void kernel_launch(void* const* d_in, const int* in_sizes, int n_in,
                              void* d_out, int out_size, void* d_ws, size_t ws_size,
                              hipStream_t stream) {
    const float* scores = (const float*)d_in[0];   // [4,1024,80]
    const float* boxes  = (const float*)d_in[1];   // [4,1024,1,4]
    float* ws_score = (float*)d_ws;
    int*   ws_idx   = (int*)((char*)d_ws + (size_t)B_IMG * C_CLS * K_PER * sizeof(float));

    nms_per_class<<<dim3(B_IMG * C_CLS), dim3(256), 0, stream>>>(
        scores, boxes, ws_score, ws_idx);
    final_topk<<<dim3(B_IMG), dim3(1024), 0, stream>>>(
        ws_score, ws_idx, boxes, (float*)d_out);
}

// Round 2
// 181.728 us; speedup vs baseline: 2.1416x; 2.1416x over previous
//
#include <hip/hip_runtime.h>
#include <stdint.h>

#define N_BOX 1024
#define C_CLS 80
#define B_IMG 4
#define K_PER 100
#define K_TOT 300
#define NEGF  (-1e30f)
#define NWORD 16                 // 1024 bits / 64
#define NCAND (C_CLS * K_PER)    // 8000 candidates per image
#define M_SEL 8192               // flat-index packing base for final top-k

typedef unsigned long long u64;
typedef unsigned int u32;

// ---- monotone float <-> ordered-uint mapping (total order, bit-exact) ----
__device__ __forceinline__ u32 ford(float f) {
    u32 u = __float_as_uint(f);
    return (u & 0x80000000u) ? ~u : (u | 0x80000000u);
}
__device__ __forceinline__ float funord(u32 o) {
    u32 u = (o & 0x80000000u) ? (o ^ 0x80000000u) : ~o;
    return __uint_as_float(u);
}

// IoU matching the numpy/jax float32 arithmetic exactly: no fma contraction.
__device__ __forceinline__ float iou_f(float4 a, float4 b) {
#pragma clang fp contract(off)
    float y1a = fminf(a.x, a.z), y2a = fmaxf(a.x, a.z);
    float x1a = fminf(a.y, a.w), x2a = fmaxf(a.y, a.w);
    float y1b = fminf(b.x, b.z), y2b = fmaxf(b.x, b.z);
    float x1b = fminf(b.y, b.w), x2b = fmaxf(b.y, b.w);
    float ih = fminf(y2a, y2b) - fmaxf(y1a, y1b); ih = fmaxf(ih, 0.0f);
    float iw = fminf(x2a, x2b) - fmaxf(x1a, x1b); iw = fmaxf(iw, 0.0f);
    float inter = ih * iw;
    float aa = (y2a - y1a) * (x2a - x1a);
    float ab = (y2b - y1b) * (x2b - x1b);
    float uni = aa + ab - inter;
    uni = fmaxf(uni, 1e-12f);
    return inter / uni;
}

// ---------------------------------------------------------------------------
// Kernel A: per-image IoU bitmask matrix. Boxes are shared across classes
// (q==1), so the suppression relation is computed ONCE per image.
// masks[b][i][w] bit j' : iou(box_i, box_{w*64+j'}) > 0.5  (diagonal off)
// ---------------------------------------------------------------------------
__global__ __launch_bounds__(256) void iou_masks(
        const float* __restrict__ boxes,    // [B, N, 1, 4]
        u64* __restrict__ masks)            // [B, N, NWORD]
{
    __shared__ float4 bx[N_BOX];            // 16 KB
    const int tid = threadIdx.x;
    const int b  = blockIdx.x >> 6;         // 4 images
    const int rg = blockIdx.x & 63;         // 64 row-groups of 16 rows

    for (int n = tid; n < N_BOX; n += 256)
        bx[n] = ((const float4*)boxes)[b * N_BOX + n];
    __syncthreads();

    const int r = tid >> 4;                 // 0..15 local row
    const int w = tid & 15;                 // 0..15 word
    const int i = rg * 16 + r;
    float4 a = bx[i];
    u64 m = 0;
    const int j0 = w * 64;
    for (int jj = 0; jj < 64; ++jj) {
        int j = j0 + jj;
        if (j != i && iou_f(a, bx[j]) > 0.5f) m |= (1ull << jj);
    }
    masks[((size_t)(b * N_BOX + i)) * NWORD + w] = m;
}

// ---------------------------------------------------------------------------
// Kernel B: one block per (image, class). Stable-descending bitonic sort of
// 1024 packed keys, then a barrier-free single-wave greedy scan using the
// precomputed masks. Suppressed-set is 16 u64 words in lanes 0..15.
// ---------------------------------------------------------------------------
__global__ __launch_bounds__(256) void nms_per_class(
        const float* __restrict__ scores,   // [B, N, C]
        const u64*   __restrict__ masks,    // [B, N, NWORD]
        float* __restrict__ ws_score,       // [B*C*K_PER]
        int*   __restrict__ ws_idx)         // [B*C*K_PER]
{
    __shared__ u64 key[N_BOX];              // 8 KB
    __shared__ int kept_t[K_PER];
    __shared__ int sh_nvalid, sh_kept;

    const int tid = threadIdx.x;
    const int b = blockIdx.x / C_CLS;
    const int c = blockIdx.x % C_CLS;

    if (tid == 0) { sh_nvalid = 0; sh_kept = 0; }
    __syncthreads();

    int lv = 0;
    for (int n = tid; n < N_BOX; n += 256) {
        float s = scores[(size_t)(b * N_BOX + n) * C_CLS + c];
        bool valid = s > 0.001f;                       // SCORE_THR
        float sv = valid ? s : NEGF;
        key[n] = ((u64)ford(sv) << 32) | (u32)(N_BOX - 1 - n);  // stable ties
        lv += valid ? 1 : 0;
    }
    if (lv) atomicAdd(&sh_nvalid, lv);
    __syncthreads();

    // bitonic sort, descending on packed key
    for (int k = 2; k <= N_BOX; k <<= 1) {
        for (int j = k >> 1; j > 0; j >>= 1) {
            for (int i = tid; i < N_BOX; i += 256) {
                int ixj = i ^ j;
                if (ixj > i) {
                    u64 a = key[i], q = key[ixj];
                    if (((i & k) == 0) ? (a < q) : (a > q)) { key[i] = q; key[ixj] = a; }
                }
            }
            __syncthreads();
        }
    }

    const int nvalid = sh_nvalid;

    // single-wave greedy scan, no barriers
    if (tid < 64) {
        const int lane = tid;
        u64 sup = 0;                         // lanes 0..15 hold suppressed words
        int kept = 0;
        const u64* mrow = masks + (size_t)b * N_BOX * NWORD;

        for (int bt = 0; bt < nvalid && kept < K_PER; bt += 64) {
            int t = bt + lane;
            bool in = t < nvalid;
            u64 k = key[t & (N_BOX - 1)];
            int idx = (N_BOX - 1) - (int)(u32)(k & 0xFFFFFFFFu);  // original box id
            u64 alivemask = __ballot(in);
            while (alivemask) {
                u64 supw = __shfl(sup, idx >> 6);          // word for my box
                bool sbit = (supw >> (idx & 63)) & 1ull;
                u64 alive_now = __ballot(in && !sbit) & alivemask;
                if (!alive_now) break;                      // rest suppressed
                int t0 = __ffsll((long long)alive_now) - 1; // first kept lane
                int i0 = __shfl(idx, t0);
                if (lane == 0) kept_t[kept] = bt + t0;
                kept++;
                if (kept >= K_PER) break;
                u64 roww = 0;
                if (lane < NWORD) roww = mrow[(size_t)i0 * NWORD + lane];
                sup |= roww;
                alivemask &= ~((2ull << t0) - 1ull);        // drop lanes <= t0
            }
            if (kept >= K_PER) break;
        }
        if (lane == 0) sh_kept = kept;
    }
    __syncthreads();

    const int kept = sh_kept;
    if (tid < K_PER) {
        int ob = (b * C_CLS + c) * K_PER + tid;
        if (tid < kept) {
            u64 k = key[kept_t[tid]];
            ws_score[ob] = funord((u32)(k >> 32));
            ws_idx[ob]   = (N_BOX - 1) - (int)(u32)(k & 0xFFFFFFFFu);
        } else {
            ws_score[ob] = NEGF;
            ws_idx[ob]   = 0;
        }
    }
}

// ---------------------------------------------------------------------------
// Kernel C: one block per image. Byte-wise MSB radix-select finds the exact
// 64-bit key of the 300th-largest candidate; gather the exactly-300 winners;
// bitonic-sort 512; write outputs.
// ---------------------------------------------------------------------------
__global__ __launch_bounds__(1024) void final_topk(
        const float* __restrict__ ws_score,
        const int*   __restrict__ ws_idx,
        const float* __restrict__ boxes,    // [B, N, 1, 4]
        float* __restrict__ out)
{
    __shared__ u32 hist[256];
    __shared__ u32 sufx[256];
    __shared__ int sh_sel;
    __shared__ u32 sh_need;
    __shared__ u64 list[512];
    __shared__ int sh_cnt, sh_valid;

    const int tid = threadIdx.x;
    const int b = blockIdx.x;
    const int base = b * NCAND;

    u64 prefix = 0;
    u32 need = K_TOT;

    for (int d = 7; d >= 0; --d) {
        if (tid < 256) hist[tid] = 0;
        __syncthreads();
        for (int i = tid; i < NCAND; i += 1024) {
            u64 k = ((u64)ford(ws_score[base + i]) << 32) | (u32)(M_SEL - 1 - i);
            bool match = (d == 7) || (((k ^ prefix) >> (8 * (d + 1))) == 0);
            if (match) atomicAdd(&hist[(u32)(k >> (8 * d)) & 0xFFu], 1u);
        }
        __syncthreads();
        if (tid < 256) sufx[tid] = hist[tid];
        __syncthreads();
        for (int off = 1; off < 256; off <<= 1) {   // Hillis-Steele suffix sum
            u32 add = 0;
            if (tid < 256 && tid + off < 256) add = sufx[tid + off];
            __syncthreads();
            if (tid < 256) sufx[tid] += add;
            __syncthreads();
        }
        if (tid < 256) {
            u32 sv = sufx[tid];
            u32 sn = (tid == 255) ? 0u : sufx[tid + 1];
            if (sv >= need && sn < need) { sh_sel = tid; sh_need = need - sn; }
        }
        __syncthreads();
        prefix |= ((u64)(u32)sh_sel) << (8 * d);
        need = sh_need;
        __syncthreads();
    }
    // prefix == exact key of the 300th-largest candidate; winners = key >= prefix

    if (tid == 0) { sh_cnt = 0; sh_valid = 0; }
    if (tid < 512) list[tid] = 0;
    __syncthreads();
    for (int i = tid; i < NCAND; i += 1024) {
        u64 k = ((u64)ford(ws_score[base + i]) << 32) | (u32)(M_SEL - 1 - i);
        if (k >= prefix) { int p = atomicAdd(&sh_cnt, 1); list[p] = k; }
    }
    __syncthreads();

    // bitonic sort 512, descending (pads are 0 -> sort last)
    for (int k2 = 2; k2 <= 512; k2 <<= 1) {
        for (int j = k2 >> 1; j > 0; j >>= 1) {
            if (tid < 512) {
                int i = tid, ixj = i ^ j;
                if (ixj > i) {
                    u64 a = list[i], q = list[ixj];
                    if (((i & k2) == 0) ? (a < q) : (a > q)) { list[i] = q; list[ixj] = a; }
                }
            }
            __syncthreads();
        }
    }

    float* out_s = out;                         // [B,300]
    float* out_b = out + B_IMG * K_TOT;         // [B,300,4]
    float* out_c = out + B_IMG * K_TOT * 5;     // [B,300]
    float* out_n = out + B_IMG * K_TOT * 6;     // [B]

    if (tid < K_TOT) {
        u64 k = list[tid];
        float s = funord((u32)(k >> 32));
        int flat = (M_SEL - 1) - (int)(u32)(k & 0xFFFFFFFFu);
        bool valid = s > (-5e29f);              // top_s > NEG/2
        float os = 0.0f, oc = 0.0f;
        float4 ob = make_float4(0.0f, 0.0f, 0.0f, 0.0f);
        if (valid) {
            int cc = flat / K_PER;
            int n  = ws_idx[base + flat];
            float4 bb = ((const float4*)boxes)[b * N_BOX + n];
            os = s;
            oc = (float)cc;
            ob.x = fminf(fmaxf(bb.x, 0.0f), 1.0f);
            ob.y = fminf(fmaxf(bb.y, 0.0f), 1.0f);
            ob.z = fminf(fmaxf(bb.z, 0.0f), 1.0f);
            ob.w = fminf(fmaxf(bb.w, 0.0f), 1.0f);
            atomicAdd(&sh_valid, 1);
        }
        out_s[b * K_TOT + tid] = os;
        ((float4*)out_b)[b * K_TOT + tid] = ob;
        out_c[b * K_TOT + tid] = oc;
    }
    __syncthreads();
    if (tid == 0) out_n[b] = (float)sh_valid;
}

extern "C" void kernel_launch(void* const* d_in, const int* in_sizes, int n_in,
                              void* d_out, int out_size, void* d_ws, size_t ws_size,
                              hipStream_t stream) {
    const float* scores = (const float*)d_in[0];   // [4,1024,80]
    const float* boxes  = (const float*)d_in[1];   // [4,1024,1,4]

    float* ws_score = (float*)d_ws;                                        // 128000 B
    int*   ws_idx   = (int*)((char*)d_ws + (size_t)B_IMG * NCAND * 4);     // 128000 B
    u64*   masks    = (u64*)((char*)d_ws + (size_t)B_IMG * NCAND * 8);     // 512 KB

    iou_masks<<<dim3(B_IMG * 64), dim3(256), 0, stream>>>(boxes, masks);
    nms_per_class<<<dim3(B_IMG * C_CLS), dim3(256), 0, stream>>>(
        scores, masks, ws_score, ws_idx);
    final_topk<<<dim3(B_IMG), dim3(1024), 0, stream>>>(
        ws_score, ws_idx, boxes, (float*)d_out);
}